// Round 11
// baseline (130.148 us; speedup 1.0000x reference)
//
#include <hip/hip_runtime.h>

#define Bb 4
#define Qn 256
#define Kn 1024
#define Hn 128

// Projections pre-scaled by 2*log2(e) and exponentiated: Eq=2^(s*qp), Ek=2^(s*kp)
// => e^{2(qp+kp)} = Eq*Ek, and tanh(qp+kp) = 1 - 2/(1+Eq*Ek).
constexpr float SCALE = 2.88539008177792681f;  // 2*log2(e)

#if __has_builtin(__builtin_amdgcn_exp2f)
#define EXP2F(x) __builtin_amdgcn_exp2f(x)
#else
#define EXP2F(x) exp2f(x)
#endif
#if __has_builtin(__builtin_amdgcn_rcpf)
#define RCPF(x) __builtin_amdgcn_rcpf(x)
#else
#define RCPF(x) (1.0f / (x))
#endif

// ---------------------------------------------------------------------------
// K1: fused projections. Blocks [0, Bb*Qn/4): query -> eq ROW-MAJOR [b,q,h]
// (contiguous per-block scalar reads in K2). Blocks [Bb*Qn/4, ...): key ->
// ekT TRANSPOSED [b,h,k] (coalesced per-lane reads in K2). Both exp2-scaled.
// ---------------------------------------------------------------------------
__global__ __launch_bounds__(128) void proj_kernel(const float* __restrict__ query,
                                                   const float* __restrict__ key,
                                                   const float* __restrict__ Wq,
                                                   const float* __restrict__ Wk,
                                                   float* __restrict__ eq,
                                                   float* __restrict__ ekT) {
    __shared__ float4 xs[128];  // 4 rows x 32 float4
    const int tid = threadIdx.x;
    const bool isQ = blockIdx.x < (Bb * Qn / 4);
    const int r0 = (isQ ? blockIdx.x : blockIdx.x - Bb * Qn / 4) * 4;
    const float* x = isQ ? query : key;
    const float* W = isQ ? Wq : Wk;

    xs[tid] = ((const float4*)(x + (size_t)r0 * Hn))[tid];
    __syncthreads();
    const float4* W4 = (const float4*)W + (size_t)tid * (Hn / 4);
    float acc0 = 0.f, acc1 = 0.f, acc2 = 0.f, acc3 = 0.f;
#pragma unroll 8
    for (int d = 0; d < Hn / 4; ++d) {
        float4 w = W4[d];
        float4 a0 = xs[d];
        float4 a1 = xs[32 + d];
        float4 a2 = xs[64 + d];
        float4 a3 = xs[96 + d];
        acc0 = fmaf(w.x, a0.x, fmaf(w.y, a0.y, fmaf(w.z, a0.z, fmaf(w.w, a0.w, acc0))));
        acc1 = fmaf(w.x, a1.x, fmaf(w.y, a1.y, fmaf(w.z, a1.z, fmaf(w.w, a1.w, acc1))));
        acc2 = fmaf(w.x, a2.x, fmaf(w.y, a2.y, fmaf(w.z, a2.z, fmaf(w.w, a2.w, acc2))));
        acc3 = fmaf(w.x, a3.x, fmaf(w.y, a3.y, fmaf(w.z, a3.z, fmaf(w.w, a3.w, acc3))));
    }
    if (isQ) {
        eq[(size_t)(r0 + 0) * Hn + tid] = EXP2F(acc0 * SCALE);
        eq[(size_t)(r0 + 1) * Hn + tid] = EXP2F(acc1 * SCALE);
        eq[(size_t)(r0 + 2) * Hn + tid] = EXP2F(acc2 * SCALE);
        eq[(size_t)(r0 + 3) * Hn + tid] = EXP2F(acc3 * SCALE);
    } else {
        const int b = r0 / Kn;
        const int k0 = r0 % Kn;
        float4 res = make_float4(EXP2F(acc0 * SCALE), EXP2F(acc1 * SCALE),
                                 EXP2F(acc2 * SCALE), EXP2F(acc3 * SCALE));
        ((float4*)ekT)[((size_t)b * Hn + tid) * (Kn / 4) + (k0 >> 2)] = res;
    }
}

// ---------------------------------------------------------------------------
// K2: score + softmax for ONE q-row per block. Grid (Qn, Bb) = 1024 blocks
// (4/CU issued, 2 resident at 16 waves) -> 2x the latency hiding of the
// fused version, 4x smaller per-thread work. Thread = k.
//   a[k] = sum_h v[h] * rcp(fma(Eq[q][h], Ek[h][k], 1))
//   softmax: min-reduce a (score = V - 2a is shift-invariant), exp2, sum.
// eq row + v are block-uniform contiguous -> s_load batches.
// mask skipped: -1e-9*(1-mask) perturbs weights by ~1e-12.
// ---------------------------------------------------------------------------
__global__ __launch_bounds__(1024) void score_softmax_kernel(const float* __restrict__ eq,
                                                             const float* __restrict__ ekT,
                                                             const float* __restrict__ v,
                                                             float* __restrict__ attn) {
    const int k = threadIdx.x;
    const int q = blockIdx.x;
    const int b = blockIdx.y;

    __shared__ float red[16][2];

    const float* eqrow = eq + ((size_t)b * Qn + q) * Hn;  // contiguous, uniform
    const float* ekb = ekT + (size_t)b * Hn * Kn + k;     // per-lane, coalesced

    float a = 0.f;
#pragma unroll 16
    for (int h = 0; h < Hn; ++h) {
        const float qe = eqrow[h];              // uniform -> s_load
        const float vh = v[h];                  // uniform -> s_load
        const float kv = ekb[(size_t)h * Kn];   // coalesced dword
        const float r = RCPF(fmaf(qe, kv, 1.0f));
        a = fmaf(vh, r, a);
    }

    // softmax over 1024 k (16 waves)
    const int lane = k & 63, wv = k >> 6;
    float mn = a;
#pragma unroll
    for (int off = 32; off; off >>= 1) mn = fminf(mn, __shfl_xor(mn, off));
    if (lane == 0) red[wv][0] = mn;
    __syncthreads();
    mn = red[0][0];
#pragma unroll
    for (int w = 1; w < 16; ++w) mn = fminf(mn, red[w][0]);

    const float e = EXP2F((mn - a) * SCALE);
    float s = e;
#pragma unroll
    for (int off = 32; off; off >>= 1) s += __shfl_xor(s, off);
    if (lane == 0) red[wv][1] = s;
    __syncthreads();
    s = red[0][1];
#pragma unroll
    for (int w = 1; w < 16; ++w) s += red[w][1];

    attn[((size_t)b * Qn + q) * Kn + k] = e * RCPF(s);
}

// ---------------------------------------------------------------------------
// K3: context. Block = (b, 4 q-rows), 1024 thr. Grid = 256 blocks.
// thread = (kc = tid>>7 split-k, cq = (tid>>5)&3, h4 = tid&31 float4-h).
// Weights read from attn (L2); value float4 coalesced; LDS partial reduce.
// ---------------------------------------------------------------------------
__global__ __launch_bounds__(1024) void ctx_kernel(const float* __restrict__ attn,
                                                   const float* __restrict__ value,
                                                   float* __restrict__ ctx) {
    const int tid = threadIdx.x;
    const int q0 = blockIdx.x * 4;
    const int b = blockIdx.y;

    __shared__ __align__(16) float4 pl[8][4][Hn / 4];  // [kc][q][h4]

    const int kc = tid >> 7;        // 0..7: k in [kc*128, +128)
    const int cq = (tid >> 5) & 3;  // q row
    const int h4 = tid & 31;        // float4 index over h
    const float4* vb = (const float4*)(value + ((size_t)b * Kn + kc * 128) * Hn) + h4;
    const float* wr = attn + ((size_t)b * Qn + q0 + cq) * Kn + kc * 128;
    float4 acc = make_float4(0.f, 0.f, 0.f, 0.f);
#pragma unroll 4
    for (int kk = 0; kk < 128; ++kk) {
        const float wgt = wr[kk];  // uniform across the 32 h4-lanes
        const float4 vv = vb[(size_t)kk * (Hn / 4)];
        acc.x = fmaf(wgt, vv.x, acc.x);
        acc.y = fmaf(wgt, vv.y, acc.y);
        acc.z = fmaf(wgt, vv.z, acc.z);
        acc.w = fmaf(wgt, vv.w, acc.w);
    }
    pl[kc][cq][h4] = acc;
    __syncthreads();
    if (tid < 128) {
        const int q = tid >> 5, h = tid & 31;
        float4 r0 = pl[0][q][h], r1 = pl[1][q][h], r2 = pl[2][q][h], r3 = pl[3][q][h];
        float4 r4 = pl[4][q][h], r5 = pl[5][q][h], r6 = pl[6][q][h], r7 = pl[7][q][h];
        float4 sum;
        sum.x = ((r0.x + r1.x) + (r2.x + r3.x)) + ((r4.x + r5.x) + (r6.x + r7.x));
        sum.y = ((r0.y + r1.y) + (r2.y + r3.y)) + ((r4.y + r5.y) + (r6.y + r7.y));
        sum.z = ((r0.z + r1.z) + (r2.z + r3.z)) + ((r4.z + r5.z) + (r6.z + r7.z));
        sum.w = ((r0.w + r1.w) + (r2.w + r3.w)) + ((r4.w + r5.w) + (r6.w + r7.w));
        ((float4*)(ctx + ((size_t)b * Qn + q0 + q) * Hn))[h] = sum;
    }
}

// ---------------------------------------------------------------------------
extern "C" void kernel_launch(void* const* d_in, const int* in_sizes, int n_in,
                              void* d_out, int out_size, void* d_ws, size_t ws_size,
                              hipStream_t stream) {
    const float* query = (const float*)d_in[0];  // (4,256,128)
    const float* key = (const float*)d_in[1];    // (4,1024,128)
    const float* value = (const float*)d_in[2];  // (4,1024,128)
    // d_in[3] = mask: unused (NEG_MASK_SCALE = -1e-9 -> effect ~1e-12)
    const float* Wq = (const float*)d_in[4];
    const float* Wk = (const float*)d_in[5];
    const float* v = (const float*)d_in[6];

    float* out = (float*)d_out;
    float* attn = out;                        // B*Q*K floats
    float* ctx = out + (size_t)Bb * Qn * Kn;  // B*Q*H floats

    float* ws = (float*)d_ws;
    float* eq = ws;             // 131072 floats: exp2(SCALE*qp), [b,q,h]
    float* ekT = ws + 131072;   // 524288 floats: exp2(SCALE*kp), [b,h,k]

    proj_kernel<<<dim3(Bb * Qn / 4 + Bb * Kn / 4), dim3(128), 0, stream>>>(
        query, key, Wq, Wk, eq, ekT);
    score_softmax_kernel<<<dim3(Qn, Bb), dim3(1024), 0, stream>>>(
        eq, ekT, v, attn);
    ctx_kernel<<<dim3(Qn / 4, Bb), dim3(1024), 0, stream>>>(
        attn, value, ctx);
}

// Round 12
// 129.753 us; speedup vs baseline: 1.0030x; 1.0030x over previous
//
#include <hip/hip_runtime.h>

#define Bb 4
#define Qn 256
#define Kn 1024
#define Hn 128

// Projections pre-scaled by 2*log2(e) and exponentiated: Eq=2^(s*qp), Ek=2^(s*kp)
// => e^{2(qp+kp)} = Eq*Ek, and tanh(qp+kp) = 1 - 2/(1+Eq*Ek).
constexpr float SCALE = 2.88539008177792681f;  // 2*log2(e)

#if __has_builtin(__builtin_amdgcn_exp2f)
#define EXP2F(x) __builtin_amdgcn_exp2f(x)
#else
#define EXP2F(x) exp2f(x)
#endif
#if __has_builtin(__builtin_amdgcn_rcpf)
#define RCPF(x) __builtin_amdgcn_rcpf(x)
#else
#define RCPF(x) (1.0f / (x))
#endif

// ---------------------------------------------------------------------------
// K1: fused projections. query -> eq ROW-MAJOR [b,q,h]; key -> ekT [b,h,k].
// Both exp2-scaled.
// ---------------------------------------------------------------------------
__global__ __launch_bounds__(128) void proj_kernel(const float* __restrict__ query,
                                                   const float* __restrict__ key,
                                                   const float* __restrict__ Wq,
                                                   const float* __restrict__ Wk,
                                                   float* __restrict__ eq,
                                                   float* __restrict__ ekT) {
    __shared__ float4 xs[128];  // 4 rows x 32 float4
    const int tid = threadIdx.x;
    const bool isQ = blockIdx.x < (Bb * Qn / 4);
    const int r0 = (isQ ? blockIdx.x : blockIdx.x - Bb * Qn / 4) * 4;
    const float* x = isQ ? query : key;
    const float* W = isQ ? Wq : Wk;

    xs[tid] = ((const float4*)(x + (size_t)r0 * Hn))[tid];
    __syncthreads();
    const float4* W4 = (const float4*)W + (size_t)tid * (Hn / 4);
    float acc0 = 0.f, acc1 = 0.f, acc2 = 0.f, acc3 = 0.f;
#pragma unroll 8
    for (int d = 0; d < Hn / 4; ++d) {
        float4 w = W4[d];
        float4 a0 = xs[d];
        float4 a1 = xs[32 + d];
        float4 a2 = xs[64 + d];
        float4 a3 = xs[96 + d];
        acc0 = fmaf(w.x, a0.x, fmaf(w.y, a0.y, fmaf(w.z, a0.z, fmaf(w.w, a0.w, acc0))));
        acc1 = fmaf(w.x, a1.x, fmaf(w.y, a1.y, fmaf(w.z, a1.z, fmaf(w.w, a1.w, acc1))));
        acc2 = fmaf(w.x, a2.x, fmaf(w.y, a2.y, fmaf(w.z, a2.z, fmaf(w.w, a2.w, acc2))));
        acc3 = fmaf(w.x, a3.x, fmaf(w.y, a3.y, fmaf(w.z, a3.z, fmaf(w.w, a3.w, acc3))));
    }
    if (isQ) {
        eq[(size_t)(r0 + 0) * Hn + tid] = EXP2F(acc0 * SCALE);
        eq[(size_t)(r0 + 1) * Hn + tid] = EXP2F(acc1 * SCALE);
        eq[(size_t)(r0 + 2) * Hn + tid] = EXP2F(acc2 * SCALE);
        eq[(size_t)(r0 + 3) * Hn + tid] = EXP2F(acc3 * SCALE);
    } else {
        const int b = r0 / Kn;
        const int k0 = r0 % Kn;
        float4 res = make_float4(EXP2F(acc0 * SCALE), EXP2F(acc1 * SCALE),
                                 EXP2F(acc2 * SCALE), EXP2F(acc3 * SCALE));
        ((float4*)ekT)[((size_t)b * Hn + tid) * (Kn / 4) + (k0 >> 2)] = res;
    }
}

// ---------------------------------------------------------------------------
// K2: scores with REGISTER-RESIDENT Ek. Block = 256 thr, thread = one k.
// Grid (qc=64 x kc=4 x b=4) = 1024 blocks = 16 waves/CU. Each thread loads
// its ekT column half (64 dwords -> 64 VGPRs, all issued back-to-back so
// latency is amortized 64-ways), then the h-loop is PURE VALU: per element
// rcp + 2 fma with s_load (SGPR) broadcast operands. Zero vector memory,
// zero LDS in the inner loop. Two sequential h-halves reuse the same regs.
//   a[q,k] = sum_h v[h] * rcp(fma(Eq[q,h], Ek[h,k], 1))
// mask skipped: -1e-9*(1-mask) perturbs weights by ~1e-12.
// ---------------------------------------------------------------------------
__global__ __launch_bounds__(256) void score_kernel(const float* __restrict__ eq,
                                                    const float* __restrict__ ekT,
                                                    const float* __restrict__ v,
                                                    float* __restrict__ scores) {
    const int tid = threadIdx.x;
    const int q0 = blockIdx.x * 4;
    const int kc = blockIdx.y;
    const int b = blockIdx.z;
    const int k = kc * 256 + tid;

    const float* ekb = ekT + (size_t)b * Hn * Kn + k;
    const float* eqb = eq + ((size_t)b * Qn + q0) * Hn;

    float a0 = 0.f, a1 = 0.f, a2 = 0.f, a3 = 0.f;
    float ek[64];

#pragma unroll
    for (int half = 0; half < 2; ++half) {
        const int hb = half * 64;
        // 64 coalesced loads, no dependent use until all issued
#pragma unroll
        for (int j = 0; j < 64; ++j) ek[j] = ekb[(size_t)(hb + j) * Kn];
        // pure-VALU accumulation (operands qe/vh are wave-uniform s_loads)
#pragma unroll
        for (int j = 0; j < 64; ++j) {
            const float vh = v[hb + j];
            const float e = ek[j];
            float r;
            r = RCPF(fmaf(eqb[0 * Hn + hb + j], e, 1.0f)); a0 = fmaf(vh, r, a0);
            r = RCPF(fmaf(eqb[1 * Hn + hb + j], e, 1.0f)); a1 = fmaf(vh, r, a1);
            r = RCPF(fmaf(eqb[2 * Hn + hb + j], e, 1.0f)); a2 = fmaf(vh, r, a2);
            r = RCPF(fmaf(eqb[3 * Hn + hb + j], e, 1.0f)); a3 = fmaf(vh, r, a3);
        }
    }

    float* srow = scores + ((size_t)b * Qn + q0) * Kn + k;
    srow[0 * Kn] = a0;
    srow[1 * Kn] = a1;
    srow[2 * Kn] = a2;
    srow[3 * Kn] = a3;
}

// ---------------------------------------------------------------------------
// K3: softmax over K=1024 per (b,q) row, reading raw a-scores.
// score = V - 2a is shift-invariant -> min-reduce a; w = 2^((amin-a)*SCALE).
// ---------------------------------------------------------------------------
__global__ __launch_bounds__(1024) void softmax_kernel(const float* __restrict__ scores,
                                                       float* __restrict__ attn) {
    const int k = threadIdx.x;
    const int q = blockIdx.x;
    const int b = blockIdx.y;

    __shared__ float red[16][2];

    const float a = scores[((size_t)b * Qn + q) * Kn + k];

    const int lane = k & 63, wv = k >> 6;
    float mn = a;
#pragma unroll
    for (int off = 32; off; off >>= 1) mn = fminf(mn, __shfl_xor(mn, off));
    if (lane == 0) red[wv][0] = mn;
    __syncthreads();
    mn = red[0][0];
#pragma unroll
    for (int w = 1; w < 16; ++w) mn = fminf(mn, red[w][0]);

    const float e = EXP2F((mn - a) * SCALE);
    float s = e;
#pragma unroll
    for (int off = 32; off; off >>= 1) s += __shfl_xor(s, off);
    if (lane == 0) red[wv][1] = s;
    __syncthreads();
    s = red[0][1];
#pragma unroll
    for (int w = 1; w < 16; ++w) s += red[w][1];

    attn[((size_t)b * Qn + q) * Kn + k] = e * RCPF(s);
}

// ---------------------------------------------------------------------------
// K4: context. Block = (b, 4 q-rows), 1024 thr. Grid = 256 blocks.
// thread = (kc split-k, cq q-row, h4 float4-h); LDS partial reduce.
// ---------------------------------------------------------------------------
__global__ __launch_bounds__(1024) void ctx_kernel(const float* __restrict__ attn,
                                                   const float* __restrict__ value,
                                                   float* __restrict__ ctx) {
    const int tid = threadIdx.x;
    const int q0 = blockIdx.x * 4;
    const int b = blockIdx.y;

    __shared__ __align__(16) float4 pl[8][4][Hn / 4];  // [kc][q][h4]

    const int kc = tid >> 7;        // 0..7: k in [kc*128, +128)
    const int cq = (tid >> 5) & 3;  // q row
    const int h4 = tid & 31;        // float4 index over h
    const float4* vb = (const float4*)(value + ((size_t)b * Kn + kc * 128) * Hn) + h4;
    const float* wr = attn + ((size_t)b * Qn + q0 + cq) * Kn + kc * 128;
    float4 acc = make_float4(0.f, 0.f, 0.f, 0.f);
#pragma unroll 4
    for (int kk = 0; kk < 128; ++kk) {
        const float wgt = wr[kk];  // uniform across the 32 h4-lanes
        const float4 vv = vb[(size_t)kk * (Hn / 4)];
        acc.x = fmaf(wgt, vv.x, acc.x);
        acc.y = fmaf(wgt, vv.y, acc.y);
        acc.z = fmaf(wgt, vv.z, acc.z);
        acc.w = fmaf(wgt, vv.w, acc.w);
    }
    pl[kc][cq][h4] = acc;
    __syncthreads();
    if (tid < 128) {
        const int q = tid >> 5, h = tid & 31;
        float4 r0 = pl[0][q][h], r1 = pl[1][q][h], r2 = pl[2][q][h], r3 = pl[3][q][h];
        float4 r4 = pl[4][q][h], r5 = pl[5][q][h], r6 = pl[6][q][h], r7 = pl[7][q][h];
        float4 sum;
        sum.x = ((r0.x + r1.x) + (r2.x + r3.x)) + ((r4.x + r5.x) + (r6.x + r7.x));
        sum.y = ((r0.y + r1.y) + (r2.y + r3.y)) + ((r4.y + r5.y) + (r6.y + r7.y));
        sum.z = ((r0.z + r1.z) + (r2.z + r3.z)) + ((r4.z + r5.z) + (r6.z + r7.z));
        sum.w = ((r0.w + r1.w) + (r2.w + r3.w)) + ((r4.w + r5.w) + (r6.w + r7.w));
        ((float4*)(ctx + ((size_t)b * Qn + q0 + q) * Hn))[h] = sum;
    }
}

// ---------------------------------------------------------------------------
extern "C" void kernel_launch(void* const* d_in, const int* in_sizes, int n_in,
                              void* d_out, int out_size, void* d_ws, size_t ws_size,
                              hipStream_t stream) {
    const float* query = (const float*)d_in[0];  // (4,256,128)
    const float* key = (const float*)d_in[1];    // (4,1024,128)
    const float* value = (const float*)d_in[2];  // (4,1024,128)
    // d_in[3] = mask: unused (NEG_MASK_SCALE = -1e-9 -> effect ~1e-12)
    const float* Wq = (const float*)d_in[4];
    const float* Wk = (const float*)d_in[5];
    const float* v = (const float*)d_in[6];

    float* out = (float*)d_out;
    float* attn = out;                        // B*Q*K floats
    float* ctx = out + (size_t)Bb * Qn * Kn;  // B*Q*H floats

    float* ws = (float*)d_ws;
    float* eq = ws;                      // 131072 floats: exp2(SCALE*qp), [b,q,h]
    float* ekT = ws + 131072;            // 524288 floats: exp2(SCALE*kp), [b,h,k]
    float* scores = ws + 131072 + 524288;  // 1048576 floats: raw a-scores

    proj_kernel<<<dim3(Bb * Qn / 4 + Bb * Kn / 4), dim3(128), 0, stream>>>(
        query, key, Wq, Wk, eq, ekT);
    score_kernel<<<dim3(Qn / 4, Kn / 256, Bb), dim3(256), 0, stream>>>(
        eq, ekT, v, scores);
    softmax_kernel<<<dim3(Qn, Bb), dim3(1024), 0, stream>>>(scores, attn);
    ctx_kernel<<<dim3(Qn / 4, Bb), dim3(1024), 0, stream>>>(attn, value, ctx);
}